// Round 6
// baseline (45.762 us; speedup 1.0000x reference)
//
#include <hip/hip_runtime.h>
#include <hip/hip_bf16.h>

// Bundle-adjustment residual.
// R6: R5 structure (poses in LDS, packed patch4 table in ws), but the pose
// staging is now a LINEAR COALESCED float4 copy (R5 staged via lane-stride-112B
// scalar loads -> every staging instr touched 64 cache lines, TA-serialized).
// LDS layout = raw poses, row-major stride 7 dwords (coprime with 32 banks).
// Quaternion normalization moved into the main loop (VALU has headroom).

#define NPOSES      4096
#define NPATCHES    262144
#define POSE_DWORDS (NPOSES * 7)          // 28672 dwords = 112 KB
#define POSE_VEC4   (POSE_DWORDS / 4)     // 7168 float4

typedef float fvec4 __attribute__((ext_vector_type(4)));
typedef int   ivec4 __attribute__((ext_vector_type(4)));

__global__ __launch_bounds__(256) void pack_patches_kernel(
    const float* __restrict__ patch_coords, const float* __restrict__ elev,
    fvec4* __restrict__ patch4, int n)
{
    int i = blockIdx.x * blockDim.x + threadIdx.x;
    if (i >= n) return;
    float2 pc = *reinterpret_cast<const float2*>(patch_coords + (size_t)i * 2);
    patch4[i] = (fvec4){pc.x, pc.y, elev[i], 0.0f};
}

// Main kernel: poses in LDS (linear copy), 4 obs per thread, 1024 thr/block.
__global__ __launch_bounds__(1024) void ba_lds_kernel(
    const float* __restrict__ poses,    // [4096,7] raw
    const fvec4* __restrict__ patch4,   // [NPATCHES] packed (x,y,elev,0)
    const int*   __restrict__ poses_idx,
    const int*   __restrict__ patch_idx,
    const float* __restrict__ target,   // [NOBS,3]
    const float* __restrict__ weights,  // [NOBS,1]
    float*       __restrict__ out,      // [NOBS,3]
    int n4)                             // NOBS/4
{
    extern __shared__ float lds[];      // POSE_DWORDS floats = 112 KB
    int tid = threadIdx.x;

    // Coalesced linear staging: 7168 float4, 1024 threads -> 7 each.
    {
        const fvec4* src = reinterpret_cast<const fvec4*>(poses);
        fvec4* dst = reinterpret_cast<fvec4*>(lds);
#pragma unroll
        for (int j = 0; j < POSE_VEC4 / 1024; ++j) {
            int idx = tid + j * 1024;
            dst[idx] = src[idx];
        }
    }
    __syncthreads();

    int i4 = blockIdx.x * blockDim.x + tid;
    if (i4 >= n4) return;

    // Streaming loads (non-temporal: keep patch table resident in L2).
    ivec4 pidx = __builtin_nontemporal_load(reinterpret_cast<const ivec4*>(poses_idx) + i4);
    ivec4 qidx = __builtin_nontemporal_load(reinterpret_cast<const ivec4*>(patch_idx) + i4);
    fvec4 w4   = __builtin_nontemporal_load(reinterpret_cast<const fvec4*>(weights) + i4);
    const fvec4* tg4 = reinterpret_cast<const fvec4*>(target) + (size_t)i4 * 3;
    fvec4 t0 = __builtin_nontemporal_load(tg4 + 0);
    fvec4 t1 = __builtin_nontemporal_load(tg4 + 1);
    fvec4 t2 = __builtin_nontemporal_load(tg4 + 2);

    int   pi[4] = {pidx.x, pidx.y, pidx.z, pidx.w};
    int   qi[4] = {qidx.x, qidx.y, qidx.z, qidx.w};
    float ww[4] = {w4.x, w4.y, w4.z, w4.w};
    float tg[12] = {t0.x, t0.y, t0.z, t0.w,
                    t1.x, t1.y, t1.z, t1.w,
                    t2.x, t2.y, t2.z, t2.w};

    float res[12];

#pragma unroll
    for (int k = 0; k < 4; ++k) {
        // Pose from LDS: 7 dwords at row pi[k]*7 (stride 7 coprime w/ 32 banks).
        const float* pl = lds + pi[k] * 7;
        float tx = pl[0], ty = pl[1], tz = pl[2];
        float qx = pl[3], qy = pl[4], qz = pl[5], qw = pl[6];
        float inv = rsqrtf(qx*qx + qy*qy + qz*qz + qw*qw);
        qx *= inv; qy *= inv; qz *= inv; qw *= inv;

        // Patch gather: single global divergent 16B load (L2-resident table).
        fvec4 pp = patch4[qi[k]];
        float px = pp.x, py = pp.y, pz = pp.z;

        // uv = cross(qv, pts)
        float ux = qy*pz - qz*py;
        float uy = qz*px - qx*pz;
        float uz = qx*py - qy*px;
        // cross(qv, uv)
        float cx = qy*uz - qz*uy;
        float cy = qz*ux - qx*uz;
        float cz = qx*uy - qy*ux;
        // rotated = pts + 2*(qw*uv + cross(qv,uv)) + t
        float rx = px + 2.0f*(qw*ux + cx) + tx;
        float ry = py + 2.0f*(qw*uy + cy) + ty;
        float rz = pz + 2.0f*(qw*uz + cz) + tz;

        // cart2polar (matches reference: r = sqrt(rho^2 + z^2))
        float rho = sqrtf(rx*rx + ry*ry);
        float r   = sqrtf(rho*rho + rz*rz);
        float az  = atan2f(ry, rx);
        float el  = atan2f(rz, rho);

        res[k*3 + 0] = (r  - tg[k*3 + 0]) * ww[k];
        res[k*3 + 1] = (az - tg[k*3 + 1]) * ww[k];
        res[k*3 + 2] = (el - tg[k*3 + 2]) * ww[k];
    }

    fvec4* o = reinterpret_cast<fvec4*>(out) + (size_t)i4 * 3;
    __builtin_nontemporal_store((fvec4){res[0], res[1], res[2],  res[3]},  o + 0);
    __builtin_nontemporal_store((fvec4){res[4], res[5], res[6],  res[7]},  o + 1);
    __builtin_nontemporal_store((fvec4){res[8], res[9], res[10], res[11]}, o + 2);
}

// Fallback path: all-global gathers from raw inputs (no ws needed).
__global__ __launch_bounds__(256) void ba_fallback_kernel(
    const float* __restrict__ poses, const float* __restrict__ patch_coords,
    const float* __restrict__ elev, const int* __restrict__ poses_idx,
    const int* __restrict__ patch_idx, const float* __restrict__ target,
    const float* __restrict__ weights, float* __restrict__ out, int n)
{
    int i = blockIdx.x * blockDim.x + threadIdx.x;
    if (i >= n) return;
    int pi = poses_idx[i];
    int qi = patch_idx[i];
    const float* p = poses + (size_t)pi * 7;
    float tx = p[0], ty = p[1], tz = p[2];
    float qx = p[3], qy = p[4], qz = p[5], qw = p[6];
    float inv = rsqrtf(qx*qx + qy*qy + qz*qz + qw*qw);
    qx *= inv; qy *= inv; qz *= inv; qw *= inv;
    float2 pc = *reinterpret_cast<const float2*>(patch_coords + (size_t)qi * 2);
    float px = pc.x, py = pc.y, pz = elev[qi];
    float ux = qy*pz - qz*py, uy = qz*px - qx*pz, uz = qx*py - qy*px;
    float cx = qy*uz - qz*uy, cy = qz*ux - qx*uz, cz = qx*uy - qy*ux;
    float rx = px + 2.0f*(qw*ux + cx) + tx;
    float ry = py + 2.0f*(qw*uy + cy) + ty;
    float rz = pz + 2.0f*(qw*uz + cz) + tz;
    float rho = sqrtf(rx*rx + ry*ry);
    float r   = sqrtf(rho*rho + rz*rz);
    float az  = atan2f(ry, rx);
    float el  = atan2f(rz, rho);
    float w = weights[i];
    out[(size_t)i*3+0] = (r  - target[(size_t)i*3+0]) * w;
    out[(size_t)i*3+1] = (az - target[(size_t)i*3+1]) * w;
    out[(size_t)i*3+2] = (el - target[(size_t)i*3+2]) * w;
}

extern "C" void kernel_launch(void* const* d_in, const int* in_sizes, int n_in,
                              void* d_out, int out_size, void* d_ws, size_t ws_size,
                              hipStream_t stream) {
    const float* poses        = (const float*)d_in[0];
    const float* patch_coords = (const float*)d_in[1];
    const float* elev         = (const float*)d_in[2];
    const int*   poses_idx    = (const int*)d_in[3];
    const int*   patch_idx    = (const int*)d_in[4];
    const float* target       = (const float*)d_in[5];
    const float* weights      = (const float*)d_in[6];
    float*       out          = (float*)d_out;

    int n  = in_sizes[3];  // NUM_OBS
    int n4 = n / 4;

    size_t patch_bytes = (size_t)NPATCHES * 16;          // 4 MiB
    size_t lds_bytes   = (size_t)POSE_DWORDS * 4;        // 114688 B

    // Opt in to >64KB dynamic LDS (idempotent; host-side, capture-safe).
    hipError_t attr_err = hipFuncSetAttribute(
        reinterpret_cast<const void*>(ba_lds_kernel),
        hipFuncAttributeMaxDynamicSharedMemorySize, (int)lds_bytes);

    if (attr_err == hipSuccess && ws_size >= patch_bytes) {
        fvec4* patch4 = (fvec4*)d_ws;
        pack_patches_kernel<<<(NPATCHES + 255) / 256, 256, 0, stream>>>(
            patch_coords, elev, patch4, NPATCHES);

        int block = 1024;
        int grid  = (n4 + block - 1) / block;  // 512
        ba_lds_kernel<<<grid, block, lds_bytes, stream>>>(
            poses, patch4, poses_idx, patch_idx, target, weights, out, n4);
    } else {
        ba_fallback_kernel<<<(n + 255) / 256, 256, 0, stream>>>(
            poses, patch_coords, elev, poses_idx, patch_idx, target, weights, out, n);
    }
}